// Round 1
// 299.691 us; speedup vs baseline: 1.0334x; 1.0334x over previous
//
#include <hip/hip_runtime.h>
#include <hip/hip_bf16.h>
#include <cmath>

// Problem constants (Qwen3 MoE block)
constexpr int T = 2048;   // tokens (B*S)
constexpr int H = 1024;   // hidden
constexpr int I = 768;    // intermediate
constexpr int E = 16;     // experts
constexpr int WMAX = 48;  // max M-tiles at M=128: sum ceil(n_e/128) <= 47

typedef short short8 __attribute__((ext_vector_type(8)));
typedef float f32x4  __attribute__((ext_vector_type(4)));

__device__ __forceinline__ short f2bf(float f) {
    __hip_bfloat16 h = __float2bfloat16(f);   // RNE
    return *reinterpret_cast<short*>(&h);
}

__device__ __forceinline__ short8 pack8(float4 a, float4 b) {
    short8 v = {f2bf(a.x), f2bf(a.y), f2bf(a.z), f2bf(a.w),
                f2bf(b.x), f2bf(b.y), f2bf(b.z), f2bf(b.w)};
    return v;
}

// XOR-swizzled LDS index (units: shorts). Row stride 32 bf16 = 64 B.
// Proven conflict-free (SQ_LDS_BANK_CONFLICT = 0 in prior rounds).
__device__ __forceinline__ int sw(int r, int kg) {
    return r * 32 + (((kg + (r >> 1)) & 3) << 3);
}

// Uniform prefix scan over cnt[] replaces the build_worklist kernel.
// All threads compute the same result from uniform scalar loads.
__device__ __forceinline__ bool find_item(const int* __restrict__ cnt, int bx,
                                          int& e_o, int& t0_o, int& n_o) {
    int c = 0;
    #pragma unroll
    for (int e = 0; e < E; ++e) {
        int n = cnt[e];
        int m = (n + 127) >> 7;
        if (bx < c + m) { e_o = e; t0_o = (bx - c) << 7; n_o = n; return true; }
        c += m;
    }
    return false;
}

// ------------------------------------------------------------------
// Router (fused x->bf16 conversion): block = 8 tokens x 16 experts.
// Each thread does a full-H fp32 dot; the thread whose expert index
// matches q>>4 also emits that 16-float slice of x as bf16 (the data
// is already in registers), replacing the separate cvt_x kernel.
// ------------------------------------------------------------------
__global__ __launch_bounds__(128) void router_kernel(
    const float* __restrict__ x,     // [T,H]
    const float* __restrict__ gw,    // [E,H]
    short* __restrict__ xb,          // [T,H] bf16 out
    int* __restrict__ cnt,           // [E]
    int* __restrict__ entries,       // [E,T]  value = t*2 + k
    float* __restrict__ wlist)       // [E,T]
{
    const int tid = threadIdx.x;
    const int tl = tid & 7, e = tid >> 3;
    const int t = blockIdx.x * 8 + tl;

    const float4* xr = (const float4*)(x + (size_t)t * H);
    const float4* gr = (const float4*)(gw + (size_t)e * H);
    short* xrow = xb + (size_t)t * H;

    float s0 = 0.f, s1 = 0.f;
    #pragma unroll 8
    for (int q = 0; q < 256; q += 2) {
        float4 a = xr[q],     b = gr[q];
        float4 c = xr[q + 1], d = gr[q + 1];
        s0 += a.x * b.x + a.y * b.y + a.z * b.z + a.w * b.w;
        s1 += c.x * d.x + c.y * d.y + c.z * d.z + c.w * d.w;
        if ((q >> 4) == e)
            *(short8*)(xrow + q * 4) = pack8(a, c);
    }

    __shared__ float lg[8][17];
    lg[tl][e] = s0 + s1;
    __syncthreads();

    if (tid < 8) {
        int tk = blockIdx.x * 8 + tid;
        float v1 = -3.0e38f, v2 = -3.0e38f;
        int i1 = 0, i2 = 0;
        #pragma unroll
        for (int k = 0; k < E; ++k) {
            float v = lg[tid][k];
            if (v > v1) { v2 = v1; i2 = i1; v1 = v; i1 = k; }
            else if (v > v2) { v2 = v; i2 = k; }
        }
        // renormalized top-2 softmax == softmax over the two winning logits
        float w1 = 1.f / (1.f + expf(v2 - v1));
        float w2 = 1.f - w1;
        int p = atomicAdd(&cnt[i1], 1);
        entries[i1 * T + p] = tk * 2;
        wlist[i1 * T + p] = w1;
        p = atomicAdd(&cnt[i2], 1);
        entries[i2 * T + p] = tk * 2 + 1;
        wlist[i2 * T + p] = w2;
    }
}

// ------------------------------------------------------------------
// Grouped gate/up GEMM + SwiGLU, bf16 MFMA. Tile M=128 x N=32, BK=32.
// N halved vs prior round (64->32): 2x blocks at unchanged HBM weight
// traffic (each weight row still read once per M-tile; extra x-tile
// re-reads hit L3, xb is only 4 MB). Waves 0/1 stage gate rows,
// waves 2/3 stage up rows; wave (mh,ng) owns a 64x16 output quadrant.
// ------------------------------------------------------------------
__global__ __launch_bounds__(256) void gateup_mfma(
    const short* __restrict__ xb,      // [T,H] bf16
    const float* __restrict__ gate_p,  // [E,I,H] f32
    const float* __restrict__ up_p,    // [E,I,H] f32
    const int* __restrict__ cnt,
    const int* __restrict__ entries,
    short* __restrict__ hmid)          // [2T,I] bf16, row = slot = t*2+k
{
    int e, t0, n;
    if (!find_item(cnt, blockIdx.x, e, t0, n)) return;
    const int i0 = blockIdx.y * 32;

    __shared__ short Xs[128 * 32];
    __shared__ short Gs[32 * 32];
    __shared__ short Us[32 * 32];
    __shared__ int toks[128];

    const int tid = threadIdx.x;
    if (tid < 128) {
        int r = t0 + tid;
        toks[tid] = (r < n) ? entries[e * T + r] : -1;
    }
    __syncthreads();

    const int lane = tid & 63, wave = tid >> 6;
    const int m16 = lane & 15, q = lane >> 4;
    const int mh = wave >> 1, ng = wave & 1;   // M-half, N-group

    // staging coords: X rows sr and 64+sr; one weight slot per thread
    const int sr = tid >> 2, skg = tid & 3;
    const int xt0 = toks[sr], xt1 = toks[64 + sr];
    const short* xsrc0 = xb + (size_t)((xt0 >= 0 ? xt0 : 0) >> 1) * H + skg * 8;
    const short* xsrc1 = xb + (size_t)((xt1 >= 0 ? xt1 : 0) >> 1) * H + skg * 8;
    const int wrow = (tid & 127) >> 2;         // 0..31
    const float* wsrc = (tid >= 128 ? up_p : gate_p)
        + (size_t)e * I * H + (size_t)(i0 + wrow) * H + skg * 8;
    short* wdst = (tid >= 128) ? Us : Gs;

    f32x4 accg[4], accu[4];
    #pragma unroll
    for (int a = 0; a < 4; ++a) {
        accg[a] = (f32x4){0.f, 0.f, 0.f, 0.f};
        accu[a] = (f32x4){0.f, 0.f, 0.f, 0.f};
    }

    // prologue loads (k0 = 0)
    short8 xc0 = *(const short8*)xsrc0;
    short8 xc1 = *(const short8*)xsrc1;
    float4 wc0 = *(const float4*)wsrc, wc1 = *(const float4*)(wsrc + 4);

    for (int k0 = 0; k0 < H; k0 += 32) {
        *(short8*)&Xs[sw(sr, skg)]      = xc0;
        *(short8*)&Xs[sw(64 + sr, skg)] = xc1;
        *(short8*)&wdst[sw(wrow, skg)]  = pack8(wc0, wc1);
        // prefetch next chunk (in flight during MFMA below)
        int kn = (k0 + 32 < H) ? k0 + 32 : 0;
        xc0 = *(const short8*)(xsrc0 + kn);
        xc1 = *(const short8*)(xsrc1 + kn);
        wc0 = *(const float4*)(wsrc + kn); wc1 = *(const float4*)(wsrc + kn + 4);
        __syncthreads();

        short8 bg = *(const short8*)&Gs[sw(ng * 16 + m16, q)];
        short8 bu = *(const short8*)&Us[sw(ng * 16 + m16, q)];
        #pragma unroll
        for (int mi = 0; mi < 4; ++mi) {
            short8 af = *(const short8*)&Xs[sw(mh * 64 + mi * 16 + m16, q)];
            accg[mi] = __builtin_amdgcn_mfma_f32_16x16x32_bf16(af, bg, accg[mi], 0, 0, 0);
            accu[mi] = __builtin_amdgcn_mfma_f32_16x16x32_bf16(af, bu, accu[mi], 0, 0, 0);
        }
        __syncthreads();
    }

    // epilogue: SwiGLU, scalar bf16 stores
    const int col = i0 + ng * 16 + m16;
    #pragma unroll
    for (int mi = 0; mi < 4; ++mi)
        #pragma unroll
        for (int j = 0; j < 4; ++j) {
            int row = mh * 64 + mi * 16 + q * 4 + j;
            int slot = toks[row];
            if (slot < 0) continue;
            float g = accg[mi][j];
            float u = accu[mi][j];
            float hv = g / (1.f + expf(-g)) * u;
            ((unsigned short*)hmid)[(size_t)slot * I + col] = (unsigned short)f2bf(hv);
        }
}

// ------------------------------------------------------------------
// Grouped down GEMM. Tile M=128 x N=64 (halved from 128), BK=32.
// 2x blocks; hmid (6 MB) is L3-resident so re-reads are ~free in HBM.
// f32 atomic combine (2-way contention only).
// ------------------------------------------------------------------
__global__ __launch_bounds__(256) void down_mfma(
    const short* __restrict__ hmid,    // [2T,I] bf16
    const float* __restrict__ down_p,  // [E,H,I] f32
    const int* __restrict__ cnt,
    const int* __restrict__ entries,
    const float* __restrict__ wlist,
    float* __restrict__ out)           // [T,H], pre-zeroed
{
    int e, t0, n;
    if (!find_item(cnt, blockIdx.x, e, t0, n)) return;
    const int h0 = blockIdx.y * 64;

    __shared__ short As[128 * 32];
    __shared__ short Bs[64 * 32];
    __shared__ int toks[128];
    __shared__ float wr[128];

    const int tid = threadIdx.x;
    if (tid < 128) {
        int r = t0 + tid;
        bool v = (r < n);
        toks[tid] = v ? entries[e * T + r] : -1;
        wr[tid]   = v ? wlist[e * T + r] : 0.f;
    }
    __syncthreads();

    const int lane = tid & 63, wave = tid >> 6;
    const int m16 = lane & 15, q = lane >> 4;

    const int sr = tid >> 2, skg = tid & 3;
    const int at0 = toks[sr], at1 = toks[64 + sr];
    const short* asrc0 = hmid + (size_t)(at0 >= 0 ? at0 : 0) * I + skg * 8;
    const short* asrc1 = hmid + (size_t)(at1 >= 0 ? at1 : 0) * I + skg * 8;
    const float* bsrc = down_p + (size_t)e * H * I + (size_t)(h0 + sr) * I + skg * 8;

    f32x4 acc[8];
    #pragma unroll
    for (int a = 0; a < 8; ++a) acc[a] = (f32x4){0.f, 0.f, 0.f, 0.f};

    short8 ac0 = *(const short8*)asrc0;
    short8 ac1 = *(const short8*)asrc1;
    float4 bc0 = *(const float4*)bsrc, bc1 = *(const float4*)(bsrc + 4);

    for (int k0 = 0; k0 < I; k0 += 32) {
        *(short8*)&As[sw(sr, skg)]      = ac0;
        *(short8*)&As[sw(64 + sr, skg)] = ac1;
        *(short8*)&Bs[sw(sr, skg)]      = pack8(bc0, bc1);
        int kn = (k0 + 32 < I) ? k0 + 32 : 0;
        ac0 = *(const short8*)(asrc0 + kn);
        ac1 = *(const short8*)(asrc1 + kn);
        bc0 = *(const float4*)(bsrc + kn); bc1 = *(const float4*)(bsrc + kn + 4);
        __syncthreads();

        short8 bf = *(const short8*)&Bs[sw(wave * 16 + m16, q)];
        #pragma unroll
        for (int mi = 0; mi < 8; ++mi) {
            short8 af = *(const short8*)&As[sw(mi * 16 + m16, q)];
            acc[mi] = __builtin_amdgcn_mfma_f32_16x16x32_bf16(af, bf, acc[mi], 0, 0, 0);
        }
        __syncthreads();
    }

    const int col = h0 + wave * 16 + m16;
    #pragma unroll
    for (int mi = 0; mi < 8; ++mi)
        #pragma unroll
        for (int j = 0; j < 4; ++j) {
            int row = mi * 16 + q * 4 + j;
            int slot = toks[row];
            if (slot < 0) continue;
            atomicAdd(&out[(size_t)(slot >> 1) * H + col], wr[row] * acc[mi][j]);
        }
}

extern "C" void kernel_launch(void* const* d_in, const int* in_sizes, int n_in,
                              void* d_out, int out_size, void* d_ws, size_t ws_size,
                              hipStream_t stream) {
    const float* x  = (const float*)d_in[0];   // [1,2048,1024]
    const float* gw = (const float*)d_in[1];   // [16,1024]
    const float* gp = (const float*)d_in[2];   // [16,768,1024]
    const float* up = (const float*)d_in[3];   // [16,768,1024]
    const float* dp = (const float*)d_in[4];   // [16,1024,768]
    float* out = (float*)d_out;

    char* ws = (char*)d_ws;
    int*   cnt     = (int*)ws;                       // 16 ints
    int*   entries = (int*)(ws + 2048);              // E*T ints   (128 KB)
    float* wlist   = (float*)(ws + 2048 + 131072);   // E*T floats (128 KB)
    short* xb      = (short*)(ws + 2048 + 262144);   // T*H bf16   (4 MB)
    short* hmid    = xb + (size_t)T * H;             // 2T*I bf16  (6 MB)

    hipMemsetAsync(ws, 0, 2048, stream);
    hipMemsetAsync(out, 0, (size_t)T * H * sizeof(float), stream);

    router_kernel<<<T / 8, 128, 0, stream>>>(x, gw, xb, cnt, entries, wlist);
    gateup_mfma<<<dim3(WMAX, I / 32), 256, 0, stream>>>(
        xb, gp, up, cnt, entries, hmid);
    down_mfma<<<dim3(WMAX, H / 64), 256, 0, stream>>>(
        hmid, dp, cnt, entries, wlist, out);
}